// Round 3
// baseline (207.862 us; speedup 1.0000x reference)
//
#include <hip/hip_runtime.h>
#include <math.h>

#define B_  16
#define C_  512
#define A_  64
#define CV  448     // C - A (value / z_img dims)
#define G_  256
#define HW  256
#define SMX 256     // padded S (Smax)
#define SLICE 64    // s-rows per uniform task
#define NSL  4      // SMX / SLICE

// ---------------- K1: spatial mean pool + zero Msnd (for atomics) ------------
__global__ __launch_bounds__(256) void meanpool_kernel(const float* __restrict__ Zimg,
                                                       float* __restrict__ z,
                                                       float* __restrict__ Msnd) {
  const int bid = blockIdx.x, t = threadIdx.x;
  if (t < 224)                                  // 2048 blocks x 896 floats = Msnd
    *(float4*)(Msnd + (size_t)bid * 896 + t * 4) = make_float4(0.f, 0.f, 0.f, 0.f);
  int row  = (bid << 2) + (t >> 6);             // b*C + c
  int lane = t & 63;
  const float4* p = (const float4*)(Zimg + (size_t)row * HW);
  float4 v = p[lane];
  float s = (v.x + v.y) + (v.z + v.w);
  #pragma unroll
  for (int off = 32; off > 0; off >>= 1)
    s += __shfl_down(s, off, 64);
  if (lane == 0) z[row] = s * (1.0f / HW);
}

// ---------------- K2: scores[g][s][b] for a 64-s slice (uniform tasks) -------
// grid = G_*NSL, 256 thr. thread = (s_local = t>>2, kq = t&3): 16-dim quarter
// dot for all 16 b, combined via shfl_xor(1,2). Invalid s -> -INF row.
__global__ __launch_bounds__(256, 4) void score_kernel(
    const float* __restrict__ Zsnd,
    const int*   __restrict__ pad_idx,
    const float* __restrict__ z,
    float*       __restrict__ scores,
    int Smax, int N)
{
  const int bid = blockIdx.x;
  const int g   = bid >> 2;
  const int s0  = (bid & 3) * SLICE;
  const int t   = threadIdx.x;

  __shared__ float qs[B_ * A_];     // 4 KB
  __shared__ int   idx[SLICE];

  if (t < SLICE) {
    int s = s0 + t;
    int v = (s < Smax) ? pad_idx[(size_t)g * Smax + s] : 0;
    bool ok = (s < Smax) && ((s == 0) || (v != 0)) && (v >= 0) && (v < N);
    idx[t] = ok ? v : -1;
  }
  { int b = t >> 4, a4 = t & 15;    // 16 b x 16 float4 = 256 threads
    *(float4*)(qs + b * A_ + a4 * 4) =
        *(const float4*)(z + b * C_ + CV + a4 * 4); }
  __syncthreads();

  const int s_l = t >> 2, kq = t & 3;
  const int my  = idx[s_l];

  float sc[B_];
  #pragma unroll
  for (int b = 0; b < B_; b++) sc[b] = 0.0f;

  if (my >= 0) {
    const float* kr = Zsnd + (size_t)my * C_ + CV + kq * 16;
    float4 k0 = *(const float4*)(kr + 0);
    float4 k1 = *(const float4*)(kr + 4);
    float4 k2 = *(const float4*)(kr + 8);
    float4 k3 = *(const float4*)(kr + 12);
    #pragma unroll
    for (int b = 0; b < B_; b++) {
      const float* qb = qs + b * A_ + kq * 16;
      float4 q0 = *(const float4*)(qb + 0);
      float4 q1 = *(const float4*)(qb + 4);
      float4 q2 = *(const float4*)(qb + 8);
      float4 q3 = *(const float4*)(qb + 12);
      sc[b] = q0.x * k0.x + q0.y * k0.y + q0.z * k0.z + q0.w * k0.w
            + q1.x * k1.x + q1.y * k1.y + q1.z * k1.z + q1.w * k1.w
            + q2.x * k2.x + q2.y * k2.y + q2.z * k2.z + q2.w * k2.w
            + q3.x * k3.x + q3.y * k3.y + q3.z * k3.z + q3.w * k3.w;
    }
  }
  #pragma unroll
  for (int b = 0; b < B_; b++) {
    sc[b] += __shfl_xor(sc[b], 1, 64);
    sc[b] += __shfl_xor(sc[b], 2, 64);
  }
  if (kq == 0) {
    float* out = scores + ((size_t)g * SMX + s0 + s_l) * B_;
    if (my >= 0) {
      *(float4*)(out + 0)  = make_float4(sc[0],  sc[1],  sc[2],  sc[3]);
      *(float4*)(out + 4)  = make_float4(sc[4],  sc[5],  sc[6],  sc[7]);
      *(float4*)(out + 8)  = make_float4(sc[8],  sc[9],  sc[10], sc[11]);
      *(float4*)(out + 12) = make_float4(sc[12], sc[13], sc[14], sc[15]);
    } else {
      float4 ninf = make_float4(-INFINITY, -INFINITY, -INFINITY, -INFINITY);
      *(float4*)(out + 0) = ninf; *(float4*)(out + 4) = ninf;
      *(float4*)(out + 8) = ninf; *(float4*)(out + 12) = ninf;
    }
  }
}

// ---------------- K3: per-(g,b) softmax stats (max, sum) + Mimg broadcast ----
// grid = G_, 256 thr (thread t = s).
__global__ __launch_bounds__(256) void stats_kernel(
    const float* __restrict__ scores,
    const float* __restrict__ z,
    float*       __restrict__ m_g,
    float*       __restrict__ l_g,
    float*       __restrict__ Mimg)
{
  const int g = blockIdx.x, t = threadIdx.x, lane = t & 63, wave = t >> 6;
  __shared__ float red[4][B_];
  __shared__ float red2[4][B_];

  const float* srow = scores + ((size_t)g * SMX + t) * B_;
  float sc[B_];
  #pragma unroll
  for (int i = 0; i < 4; i++) {
    float4 v = *(const float4*)(srow + i * 4);
    sc[i * 4 + 0] = v.x; sc[i * 4 + 1] = v.y; sc[i * 4 + 2] = v.z; sc[i * 4 + 3] = v.w;
  }
  #pragma unroll
  for (int b = 0; b < B_; b++) {
    float v = sc[b];
    #pragma unroll
    for (int off = 32; off > 0; off >>= 1)
      v = fmaxf(v, __shfl_xor(v, off, 64));
    if (lane == 0) red[wave][b] = v;
  }
  __syncthreads();
  #pragma unroll
  for (int b = 0; b < B_; b++) {
    float gm = fmaxf(fmaxf(red[0][b], red[1][b]), fmaxf(red[2][b], red[3][b]));
    float e  = __expf(sc[b] - gm);       // -INF rows -> 0
    #pragma unroll
    for (int off = 32; off > 0; off >>= 1)
      e += __shfl_xor(e, off, 64);
    if (lane == 0) red2[wave][b] = e;
  }
  __syncthreads();
  if (t < B_) {
    float gm = fmaxf(fmaxf(red[0][t], red[1][t]), fmaxf(red[2][t], red[3][t]));
    float gs = (red2[0][t] + red2[1][t]) + (red2[2][t] + red2[3][t]);
    m_g[g * B_ + t] = gm;
    l_g[g * B_ + t] = gs;
  }
  // Mimg[g,b,:] = z[b,:CV]  (16*448 floats = 1792 float4 = 256 thr x 7)
  #pragma unroll
  for (int i = 0; i < 7; i++) {
    int li = i * 256 + t;
    int b = li / 112, c4 = li % 112;
    *(float4*)(Mimg + (size_t)g * (B_ * CV) + b * CV + c4 * 4) =
        *(const float4*)(z + b * C_ + c4 * 4);
  }
}

// ---------------- K4: PV for (g, slice, b-half); atomic accumulate -----------
// grid = G_*NSL*2, 256 thr. bh = bid>>10 (pairs +-1024 share XCD -> L2 dedupe
// of value rows). Uniform slice work; empty slices exit early (pre-atomic).
// Waves = column chunks; lane = (cl col slot, h s-parity); 8 gathers in
// flight; acc[8] float4 (32 VGPR) -> no spill at launch_bounds(256,4).
__global__ __launch_bounds__(256, 4) void pv_kernel(
    const float* __restrict__ Zsnd,
    const int*   __restrict__ pad_idx,
    const float* __restrict__ scores,
    const float* __restrict__ m_g,
    const float* __restrict__ l_g,
    float*       __restrict__ Msnd,
    int Smax, int N)
{
  const int bid = blockIdx.x;
  const int bh  = bid >> 10;
  const int r   = bid & 1023;
  const int g   = r >> 2;
  const int s0  = (r & 3) * SLICE;
  const int b0  = bh * 8;
  const int t    = threadIdx.x;
  const int lane = t & 63;
  const int wave = t >> 6;

  __shared__ int   idx[SLICE];
  __shared__ float w[SLICE][8];     // 2 KB
  __shared__ float mls[16];         // m[0..7], rl[8..15]

  if (t < SLICE) {
    int s = s0 + t;
    int v = (s < Smax) ? pad_idx[(size_t)g * Smax + s] : 0;
    bool ok = (s < Smax) && ((s == 0) || (v != 0)) && (v >= 0) && (v < N);
    idx[t] = ok ? v : -1;
  }
  if (t < 8) {
    mls[t]     = m_g[g * B_ + b0 + t];
    mls[8 + t] = 1.0f / l_g[g * B_ + b0 + t];
  }
  __syncthreads();
  if (idx[0] < 0) return;           // prefix validity: whole slice empty

  {                                 // weights: t = (s_l, bq); invalid s -> exp(-INF)=0
    const int s_l = t & 63, bq = t >> 6;
    const float2 s2 = *(const float2*)(scores + ((size_t)g * SMX + s0 + s_l) * B_ + b0 + bq * 2);
    w[s_l][bq * 2 + 0] = __expf(s2.x - mls[bq * 2 + 0]) * mls[8 + bq * 2 + 0];
    w[s_l][bq * 2 + 1] = __expf(s2.y - mls[bq * 2 + 1]) * mls[8 + bq * 2 + 1];
    if (t < SLICE && idx[t] < 0) idx[t] = 0;   // gather-safe (weight already 0)
  }
  __syncthreads();

  const int ch = wave;              // column chunk 0..3 (chunk 3 half-valid)
  const int cl = lane & 31;
  const int h  = lane >> 5;
  const int c0 = ch * 128;

  const float* vbase = Zsnd + c0 + cl * 4;     // + idx*C_ ; col <= 508 in-row
  float4 acc[8];
  #pragma unroll
  for (int b = 0; b < 8; b++) acc[b] = make_float4(0.f, 0.f, 0.f, 0.f);

  #pragma unroll
  for (int it = 0; it < 4; it++) {
    float4 v[8];
    #pragma unroll
    for (int j = 0; j < 8; j++) {
      int s_l = it * 16 + j * 2 + h;
      v[j] = *(const float4*)(vbase + (size_t)idx[s_l] * C_);
    }
    #pragma unroll
    for (int j = 0; j < 8; j++) {
      int s_l = it * 16 + j * 2 + h;
      float4 w0 = *(const float4*)(&w[s_l][0]);   // b 0..3 (broadcast)
      float4 w1 = *(const float4*)(&w[s_l][4]);   // b 4..7
      float4 vv = v[j];
      acc[0].x += w0.x * vv.x; acc[0].y += w0.x * vv.y; acc[0].z += w0.x * vv.z; acc[0].w += w0.x * vv.w;
      acc[1].x += w0.y * vv.x; acc[1].y += w0.y * vv.y; acc[1].z += w0.y * vv.z; acc[1].w += w0.y * vv.w;
      acc[2].x += w0.z * vv.x; acc[2].y += w0.z * vv.y; acc[2].z += w0.z * vv.z; acc[2].w += w0.z * vv.w;
      acc[3].x += w0.w * vv.x; acc[3].y += w0.w * vv.y; acc[3].z += w0.w * vv.z; acc[3].w += w0.w * vv.w;
      acc[4].x += w1.x * vv.x; acc[4].y += w1.x * vv.y; acc[4].z += w1.x * vv.z; acc[4].w += w1.x * vv.w;
      acc[5].x += w1.y * vv.x; acc[5].y += w1.y * vv.y; acc[5].z += w1.y * vv.z; acc[5].w += w1.y * vv.w;
      acc[6].x += w1.z * vv.x; acc[6].y += w1.z * vv.y; acc[6].z += w1.z * vv.z; acc[6].w += w1.z * vv.w;
      acc[7].x += w1.w * vv.x; acc[7].y += w1.w * vv.y; acc[7].z += w1.w * vv.z; acc[7].w += w1.w * vv.w;
    }
  }

  #pragma unroll
  for (int b = 0; b < 8; b++) {     // fold h parity
    acc[b].x += __shfl_xor(acc[b].x, 32, 64);
    acc[b].y += __shfl_xor(acc[b].y, 32, 64);
    acc[b].z += __shfl_xor(acc[b].z, 32, 64);
    acc[b].w += __shfl_xor(acc[b].w, 32, 64);
  }
  if (h == 0 && c0 + cl * 4 < CV) {
    float* ob = Msnd + (size_t)g * (B_ * CV) + (size_t)b0 * CV + c0 + cl * 4;
    #pragma unroll
    for (int b = 0; b < 8; b++) {
      atomicAdd(ob + b * CV + 0, acc[b].x);
      atomicAdd(ob + b * CV + 1, acc[b].y);
      atomicAdd(ob + b * CV + 2, acc[b].z);
      atomicAdd(ob + b * CV + 3, acc[b].w);
    }
  }
}

extern "C" void kernel_launch(void* const* d_in, const int* in_sizes, int n_in,
                              void* d_out, int out_size, void* d_ws, size_t ws_size,
                              hipStream_t stream) {
  const float* Zimg   = (const float*)d_in[0];
  const float* Zsnd   = (const float*)d_in[1];
  const int*   padidx = (const int*)d_in[2];
  // d_in[3] = pad_mask (unused; validity derived from pad_idx)
  // d_in[4] = attn_dims (constant 64)

  const int N    = in_sizes[1] / C_;     // rows in Z_snd
  const int Smax = in_sizes[2] / G_;     // padded sequence length (== 256)

  float* z      = (float*)d_ws;                          // 8192 f32
  float* scores = z + B_ * C_;                           // G*SMX*B = 4 MB
  float* m_g    = scores + (size_t)G_ * SMX * B_;        // 4096 f32
  float* l_g    = m_g + G_ * B_;                         // 4096 f32
  float* Mimg = (float*)d_out;
  float* Msnd = Mimg + (size_t)G_ * B_ * CV;

  meanpool_kernel<<<(B_ * C_) / 4, 256, 0, stream>>>(Zimg, z, Msnd);
  score_kernel<<<G_ * NSL, 256, 0, stream>>>(Zsnd, padidx, z, scores, Smax, N);
  stats_kernel<<<G_, 256, 0, stream>>>(scores, z, m_g, l_g, Mimg);
  pv_kernel<<<G_ * NSL * 2, 256, 0, stream>>>(Zsnd, padidx, scores, m_g, l_g, Msnd, Smax, N);
}

// Round 4
// 184.407 us; speedup vs baseline: 1.1272x; 1.1272x over previous
//
#include <hip/hip_runtime.h>
#include <math.h>

#define B_  16
#define C_  512
#define A_  64
#define CV  448     // C - A (value / z_img dims)
#define G_  256
#define HW  256
#define SMX 256     // padded S (Smax)
#define BSP 8       // b-rows per block (2 blocks per group)

// ---------------- K1: spatial mean pool + per-group size ---------------------
// Blocks 0..255 additionally compute sgArr[g] = #valid s for group g.
__global__ __launch_bounds__(256) void meanpool_kernel(const float* __restrict__ Zimg,
                                                       float* __restrict__ z,
                                                       const int* __restrict__ pad_idx,
                                                       int* __restrict__ sgArr,
                                                       int Smax, int N) {
  const int bid = blockIdx.x, t = threadIdx.x;
  const int lane = t & 63, wave = t >> 6;
  __shared__ int r4[4];

  if (bid < G_) {                       // group size (prefix-contiguous validity)
    int v = pad_idx[(size_t)bid * Smax + t];
    bool ok = ((t == 0) || (v != 0)) && (v >= 0) && (v < N);
    int sgv = ok ? (t + 1) : 0;
    #pragma unroll
    for (int off = 32; off > 0; off >>= 1)
      sgv = max(sgv, __shfl_xor(sgv, off, 64));
    if (lane == 0) r4[wave] = sgv;
    __syncthreads();
    if (t == 0) sgArr[bid] = max(max(r4[0], r4[1]), max(r4[2], r4[3]));
  }

  int row = (bid << 2) + (t >> 6);      // b*C + c
  const float4* p = (const float4*)(Zimg + (size_t)row * HW);
  float4 v = p[lane];
  float s = (v.x + v.y) + (v.z + v.w);
  #pragma unroll
  for (int off = 32; off > 0; off >>= 1)
    s += __shfl_down(s, off, 64);
  if (lane == 0) z[row] = s * (1.0f / HW);
}

// ---------------- K2: bucket-rank groups by size (descending) ----------------
// 1 block, 256 thr. grank[r] = group with approx rank r (big -> small, 32-wide
// buckets). Pair sums grank[p]+grank[255-p] are near-constant for uniform
// sizes -> balanced CU loads in the fused kernel.
__global__ __launch_bounds__(256) void sched_kernel(const int* __restrict__ sgArr,
                                                    int* __restrict__ grank) {
  __shared__ int cnt[8], base[8];
  const int t = threadIdx.x;
  if (t < 8) cnt[t] = 0;
  __syncthreads();
  int sg = sgArr[t];
  int bk = min(7, max(0, sg - 32) >> 5);       // 32..256 -> 0..7
  atomicAdd(&cnt[bk], 1);
  __syncthreads();
  if (t == 0) {
    int o = 0;
    for (int b = 7; b >= 0; b--) { base[b] = o; o += cnt[b]; }
  }
  __syncthreads();
  int r = atomicAdd(&base[bk], 1);
  grank[r] = t;
}

// ---------------- K3: fused scores + softmax + PV + M_img --------------------
// grid = 512, 512 thr. Balanced mapping: p = bid&127, bh = (bid>>7)&1,
// g = (bid>>8) ? grank[255-p] : grank[p].
//  - group ranked p occupies slots {p, p+128} (bh 0/1), its partner ranked
//    255-p occupies {p+256, p+384}: all four on XCD p%8 -> key/value rows
//    deduped in that L2.
//  - CU hosting slots q and q+256 gets one big + one small group: per-CU
//    load ~ sg_big + sg_small ~ const (vs single-group 32..256 before).
// Phase A: thread (s = t>>1, kh = t&1) computes a 32-dim half-dot for 8 b
//          (skipped entirely for invalid s -> cost scales with sg);
//          combines via shfl_xor(1); block softmax; attn -> LDS (0 past sg).
// Phase B: wave = (col-chunk ch, s-parity sh); lane = (col slot cl, parity h).
//          8 gathered float4/thread in flight; attn reads broadcast;
//          cross-wave combine via LDS redS + shfl_xor(32). 60 VGPR, no spill.
__global__ __launch_bounds__(512, 4) void fused_kernel(
    const float* __restrict__ Zsnd,
    const int*   __restrict__ pad_idx,
    const float* __restrict__ z,
    const int*   __restrict__ grank,
    float*       __restrict__ Mimg,
    float*       __restrict__ Msnd,
    int Smax, int N)
{
  const int bid  = blockIdx.x;
  const int p_   = bid & 127;
  const int bh   = (bid >> 7) & 1;
  const int g    = (bid >> 8) ? grank[255 - p_] : grank[p_];
  const int b0   = bh * BSP;
  const int t    = threadIdx.x;
  const int lane = t & 63;
  const int wave = t >> 6;

  __shared__ float qs[BSP * A_];            // 2 KB
  __shared__ float attnT[SMX * BSP];        // 8 KB  [s][b-local]
  __shared__ int   idxs[SMX];               // 1 KB
  __shared__ float red[8 * BSP];
  __shared__ float red2[8 * BSP];
  __shared__ int   redi[8];
  __shared__ float redS[4 * BSP * 64 * 4];  // 32 KB [ch][b][lane] float4

  // ---- stage: validity/idx, queries, M_img broadcast ----
  int sgv = 0;
  if (t < SMX) {
    int v = pad_idx[(size_t)g * Smax + t];
    bool ok = ((t == 0) || (v != 0)) && (v >= 0) && (v < N);
    idxs[t] = ok ? v : 0;
    sgv = ok ? (t + 1) : 0;
  }
  #pragma unroll
  for (int off = 32; off > 0; off >>= 1)
    sgv = max(sgv, __shfl_xor(sgv, off, 64));
  if (lane == 0) redi[wave] = sgv;

  if (t < BSP * 16) {                       // 8 b x 16 a4 = 128 float4s
    int b = t >> 4, a4 = t & 15;
    *(float4*)(qs + b * A_ + a4 * 4) =
        *(const float4*)(z + (b0 + b) * C_ + CV + a4 * 4);
  }

  {                                         // Mimg[g, b0+b, :] = z[b0+b, :CV]
    int b = t >> 6, c = t & 63;
    float* mrow = Mimg + (size_t)g * (B_ * CV) + (b0 + b) * CV;
    const float* zrow = z + (b0 + b) * C_;
    *(float4*)(mrow + c * 4) = *(const float4*)(zrow + c * 4);
    int c2 = c + 64;
    if (c2 < 112)
      *(float4*)(mrow + c2 * 4) = *(const float4*)(zrow + c2 * 4);
  }

  __syncthreads();
  const int sg = max(max(max(redi[0], redi[1]), max(redi[2], redi[3])),
                     max(max(redi[4], redi[5]), max(redi[6], redi[7])));

  // ---- Phase A: scores (split-K over kh); skipped for invalid s ----
  const int s_ = t >> 1;
  const int kh = t & 1;
  const bool valid = (s_ < sg);             // prefix-contiguous validity
  const float* krow = Zsnd + (size_t)idxs[s_] * C_ + CV + kh * 32;

  float sc[BSP];
  #pragma unroll
  for (int b = 0; b < BSP; b++) sc[b] = 0.0f;

  if (valid) {
    #pragma unroll
    for (int c = 0; c < 2; c++) {
      float4 k0 = *(const float4*)(krow + c * 16 + 0);
      float4 k1 = *(const float4*)(krow + c * 16 + 4);
      float4 k2 = *(const float4*)(krow + c * 16 + 8);
      float4 k3 = *(const float4*)(krow + c * 16 + 12);
      #pragma unroll
      for (int b = 0; b < BSP; b++) {
        const float* qb = qs + b * A_ + kh * 32 + c * 16;
        float4 q0 = *(const float4*)(qb + 0);
        float4 q1 = *(const float4*)(qb + 4);
        float4 q2 = *(const float4*)(qb + 8);
        float4 q3 = *(const float4*)(qb + 12);
        sc[b] += q0.x * k0.x + q0.y * k0.y + q0.z * k0.z + q0.w * k0.w
               + q1.x * k1.x + q1.y * k1.y + q1.z * k1.z + q1.w * k1.w
               + q2.x * k2.x + q2.y * k2.y + q2.z * k2.z + q2.w * k2.w
               + q3.x * k3.x + q3.y * k3.y + q3.z * k3.z + q3.w * k3.w;
      }
      __builtin_amdgcn_sched_barrier(0);    // cap live values (anti-spill)
    }
  }
  #pragma unroll
  for (int b = 0; b < BSP; b++)
    sc[b] += __shfl_xor(sc[b], 1, 64);      // combine kh halves: full dot

  // ---- softmax over s (butterfly within wave, LDS across 8 waves) ----
  #pragma unroll
  for (int b = 0; b < BSP; b++) {
    float v = valid ? sc[b] : -INFINITY;
    #pragma unroll
    for (int off = 32; off > 0; off >>= 1)
      v = fmaxf(v, __shfl_xor(v, off, 64));
    if (lane == 0) red[wave * BSP + b] = v;
  }
  __syncthreads();

  float ex[BSP];
  #pragma unroll
  for (int b = 0; b < BSP; b++) {
    float gm = red[0 * BSP + b];
    #pragma unroll
    for (int w2 = 1; w2 < 8; w2++) gm = fmaxf(gm, red[w2 * BSP + b]);
    float e = valid ? __expf(sc[b] - gm) : 0.0f;
    ex[b] = e;
    float es = (kh == 0) ? e : 0.0f;        // count each s once
    #pragma unroll
    for (int off = 32; off > 0; off >>= 1)
      es += __shfl_xor(es, off, 64);
    if (lane == 0) red2[wave * BSP + b] = es;
  }
  __syncthreads();

  if (kh == 0) {
    float iv[BSP];
    #pragma unroll
    for (int b = 0; b < BSP; b++) {
      float gs = red2[0 * BSP + b];
      #pragma unroll
      for (int w2 = 1; w2 < 8; w2++) gs += red2[w2 * BSP + b];
      iv[b] = ex[b] / gs;
    }
    *(float4*)(attnT + s_ * BSP + 0) = make_float4(iv[0], iv[1], iv[2], iv[3]);
    *(float4*)(attnT + s_ * BSP + 4) = make_float4(iv[4], iv[5], iv[6], iv[7]);
  }
  __syncthreads();

  // ---- Phase B: weighted value sum (32 s per iter, 8 gathers in flight) ----
  const int ch = wave >> 1;                 // column chunk (0..3)
  const int sh = wave & 1;                  // s parity
  const int cl = lane & 31;                 // float4 column slot
  const int h  = lane >> 5;                 // s sub-parity
  const int c0 = ch * 128;
  const int sg32 = (sg + 31) & ~31;         // attnT==0 past sg -> pad is exact

  const float* vbase = Zsnd + c0 + cl * 4;  // + idx*C_ ; col <= 508 in-row
  float4 acc[BSP];
  #pragma unroll
  for (int b = 0; b < BSP; b++) acc[b] = make_float4(0.f, 0.f, 0.f, 0.f);

  for (int s0 = 0; s0 < sg32; s0 += 32) {
    float4 v[8];
    #pragma unroll
    for (int j = 0; j < 8; j++) {
      int so = s0 + 4 * j + 2 * sh + h;
      v[j] = *(const float4*)(vbase + (size_t)idxs[so] * C_);
    }
    #pragma unroll
    for (int j = 0; j < 8; j++) {
      int so = s0 + 4 * j + 2 * sh + h;
      float4 w0 = *(const float4*)(attnT + so * BSP + 0);   // b 0..3 (broadcast)
      float4 w1 = *(const float4*)(attnT + so * BSP + 4);   // b 4..7
      float4 vv = v[j];
      acc[0].x += w0.x * vv.x; acc[0].y += w0.x * vv.y; acc[0].z += w0.x * vv.z; acc[0].w += w0.x * vv.w;
      acc[1].x += w0.y * vv.x; acc[1].y += w0.y * vv.y; acc[1].z += w0.y * vv.z; acc[1].w += w0.y * vv.w;
      acc[2].x += w0.z * vv.x; acc[2].y += w0.z * vv.y; acc[2].z += w0.z * vv.z; acc[2].w += w0.z * vv.w;
      acc[3].x += w0.w * vv.x; acc[3].y += w0.w * vv.y; acc[3].z += w0.w * vv.z; acc[3].w += w0.w * vv.w;
      acc[4].x += w1.x * vv.x; acc[4].y += w1.x * vv.y; acc[4].z += w1.x * vv.z; acc[4].w += w1.x * vv.w;
      acc[5].x += w1.y * vv.x; acc[5].y += w1.y * vv.y; acc[5].z += w1.y * vv.z; acc[5].w += w1.y * vv.w;
      acc[6].x += w1.z * vv.x; acc[6].y += w1.z * vv.y; acc[6].z += w1.z * vv.z; acc[6].w += w1.z * vv.w;
      acc[7].x += w1.w * vv.x; acc[7].y += w1.w * vv.y; acc[7].z += w1.w * vv.z; acc[7].w += w1.w * vv.w;
    }
  }

  // ---- cross-wave combine: sh==1 partials -> LDS, sh==0 adds + h-shfl ----
  if (sh == 1) {
    #pragma unroll
    for (int b = 0; b < BSP; b++)
      *(float4*)(redS + (((size_t)ch * BSP + b) * 64 + lane) * 4) = acc[b];
  }
  __syncthreads();
  if (sh == 0) {
    #pragma unroll
    for (int b = 0; b < BSP; b++) {
      float4 o = *(const float4*)(redS + (((size_t)ch * BSP + b) * 64 + lane) * 4);
      acc[b].x += o.x; acc[b].y += o.y; acc[b].z += o.z; acc[b].w += o.w;
      acc[b].x += __shfl_xor(acc[b].x, 32, 64);
      acc[b].y += __shfl_xor(acc[b].y, 32, 64);
      acc[b].z += __shfl_xor(acc[b].z, 32, 64);
      acc[b].w += __shfl_xor(acc[b].w, 32, 64);
    }
    if (h == 0 && c0 + cl * 4 < CV) {
      float* obase = Msnd + (size_t)g * (B_ * CV) + (size_t)b0 * CV + c0 + cl * 4;
      #pragma unroll
      for (int b = 0; b < BSP; b++)
        *(float4*)(obase + b * CV) = acc[b];
    }
  }
}

extern "C" void kernel_launch(void* const* d_in, const int* in_sizes, int n_in,
                              void* d_out, int out_size, void* d_ws, size_t ws_size,
                              hipStream_t stream) {
  const float* Zimg   = (const float*)d_in[0];
  const float* Zsnd   = (const float*)d_in[1];
  const int*   padidx = (const int*)d_in[2];
  // d_in[3] = pad_mask (unused; validity derived from pad_idx)
  // d_in[4] = attn_dims (constant 64)

  const int N    = in_sizes[1] / C_;     // rows in Z_snd
  const int Smax = in_sizes[2] / G_;     // padded sequence length (== 256)

  float* z     = (float*)d_ws;                            // B*C fp32
  int*   sgArr = (int*)(z + B_ * C_);                     // 256 ints
  int*   grank = sgArr + G_;                              // 256 ints
  float* Mimg = (float*)d_out;
  float* Msnd = Mimg + (size_t)G_ * B_ * CV;

  meanpool_kernel<<<(B_ * C_) / 4, 256, 0, stream>>>(Zimg, z, padidx, sgArr, Smax, N);
  sched_kernel<<<1, 256, 0, stream>>>(sgArr, grank);
  fused_kernel<<<G_ * 2, 512, 0, stream>>>(Zsnd, padidx, z, grank, Mimg, Msnd, Smax, N);
}

// Round 5
// 154.194 us; speedup vs baseline: 1.3481x; 1.1959x over previous
//
#include <hip/hip_runtime.h>
#include <math.h>

#define B_  16
#define C_  512
#define A_  64
#define CV  448     // C - A (value / z_img dims)
#define G_  256
#define HW  256
#define SMX 256     // padded S (Smax)
#define BSP 8       // b-rows per block (2 blocks per group)

// ---------------- K1: spatial mean pool + per-group size ---------------------
// Blocks 0..255 additionally compute sgArr[g] = #valid s for group g.
__global__ __launch_bounds__(256) void meanpool_kernel(const float* __restrict__ Zimg,
                                                       float* __restrict__ z,
                                                       const int* __restrict__ pad_idx,
                                                       int* __restrict__ sgArr,
                                                       int Smax, int N) {
  const int bid = blockIdx.x, t = threadIdx.x;
  const int lane = t & 63, wave = t >> 6;
  __shared__ int r4[4];

  if (bid < G_) {                       // group size (prefix-contiguous validity)
    int v = pad_idx[(size_t)bid * Smax + t];
    bool ok = ((t == 0) || (v != 0)) && (v >= 0) && (v < N);
    int sgv = ok ? (t + 1) : 0;
    #pragma unroll
    for (int off = 32; off > 0; off >>= 1)
      sgv = max(sgv, __shfl_xor(sgv, off, 64));
    if (lane == 0) r4[wave] = sgv;
    __syncthreads();
    if (t == 0) sgArr[bid] = max(max(r4[0], r4[1]), max(r4[2], r4[3]));
  }

  int row = (bid << 2) + (t >> 6);      // b*C + c
  const float4* p = (const float4*)(Zimg + (size_t)row * HW);
  float4 v = p[lane];
  float s = (v.x + v.y) + (v.z + v.w);
  #pragma unroll
  for (int off = 32; off > 0; off >>= 1)
    s += __shfl_down(s, off, 64);
  if (lane == 0) z[row] = s * (1.0f / HW);
}

// ---------------- K2: bucket-rank groups by size (descending) ----------------
// 1 block, 256 thr. grank[r] = group with approx rank r (big -> small, 32-wide
// buckets). Pair sums grank[p]+grank[255-p] are near-constant for uniform
// sizes -> balanced CU loads in the fused kernel.
__global__ __launch_bounds__(256) void sched_kernel(const int* __restrict__ sgArr,
                                                    int* __restrict__ grank) {
  __shared__ int cnt[8], base[8];
  const int t = threadIdx.x;
  if (t < 8) cnt[t] = 0;
  __syncthreads();
  int sg = sgArr[t];
  int bk = min(7, max(0, sg - 32) >> 5);       // 32..256 -> 0..7
  atomicAdd(&cnt[bk], 1);
  __syncthreads();
  if (t == 0) {
    int o = 0;
    for (int b = 7; b >= 0; b--) { base[b] = o; o += cnt[b]; }
  }
  __syncthreads();
  int r = atomicAdd(&base[bk], 1);
  grank[r] = t;
}

// ---------------- K3: fused scores + softmax + PV + M_img --------------------
// Body is byte-identical to the round-1 53us kernel (60 VGPR, no spill, no
// bank conflicts). ONLY the block->(g,bh) mapping changed:
//   p = bid&127, bh = (bid>>7)&1, g = (bid>>8) ? grank[255-p] : grank[p].
//  - group ranked p occupies bids {p, p+128}, partner 255-p at {p+256,p+384}:
//    all on XCD p%8 -> key/value rows deduped in that L2 (round-1 property).
//  - likely CU co-residents (bid, bid+256) hold one big + one small group:
//    per-CU load ~ sg_big + sg_small ~ const (was 2x one group = 64..512).
// Phase A: thread (s = t>>1, kh = t&1): 32-dim half-dot for 8 b, UNCONDITIONAL
//          loads (conditional version spilled: r4 VGPR 64, +69 MB writes);
//          combine via shfl_xor(1); block softmax; attn -> LDS (0 past sg).
// Phase B: wave = (col-chunk ch, s-parity sh); lane = (col slot cl, parity h).
//          8 gathered float4/thread in flight; attn reads broadcast;
//          cross-wave combine via LDS redS + shfl_xor(32).
__global__ __launch_bounds__(512, 4) void fused_kernel(
    const float* __restrict__ Zsnd,
    const int*   __restrict__ pad_idx,
    const float* __restrict__ z,
    const int*   __restrict__ grank,
    float*       __restrict__ Mimg,
    float*       __restrict__ Msnd,
    int Smax, int N)
{
  const int bid  = blockIdx.x;
  const int p_   = bid & 127;
  const int bh   = (bid >> 7) & 1;
  const int rr   = (bid >> 8) ? (255 - p_) : p_;
  const int g    = grank[rr];
  const int b0   = bh * BSP;
  const int t    = threadIdx.x;
  const int lane = t & 63;
  const int wave = t >> 6;

  __shared__ float qs[BSP * A_];            // 2 KB
  __shared__ float attnT[SMX * BSP];        // 8 KB  [s][b-local]
  __shared__ int   idxs[SMX];               // 1 KB
  __shared__ float red[8 * BSP];
  __shared__ float red2[8 * BSP];
  __shared__ int   redi[8];
  __shared__ float redS[4 * BSP * 64 * 4];  // 32 KB [ch][b][lane] float4

  // ---- stage: validity/idx, queries, M_img broadcast ----
  int sgv = 0;
  if (t < SMX) {
    int v = pad_idx[(size_t)g * Smax + t];
    bool ok = ((t == 0) || (v != 0)) && (v >= 0) && (v < N);
    idxs[t] = ok ? v : 0;
    sgv = ok ? (t + 1) : 0;
  }
  #pragma unroll
  for (int off = 32; off > 0; off >>= 1)
    sgv = max(sgv, __shfl_xor(sgv, off, 64));
  if (lane == 0) redi[wave] = sgv;

  if (t < BSP * 16) {                       // 8 b x 16 a4 = 128 float4s
    int b = t >> 4, a4 = t & 15;
    *(float4*)(qs + b * A_ + a4 * 4) =
        *(const float4*)(z + (b0 + b) * C_ + CV + a4 * 4);
  }

  {                                         // Mimg[g, b0+b, :] = z[b0+b, :CV]
    int b = t >> 6, c = t & 63;
    float* mrow = Mimg + (size_t)g * (B_ * CV) + (b0 + b) * CV;
    const float* zrow = z + (b0 + b) * C_;
    *(float4*)(mrow + c * 4) = *(const float4*)(zrow + c * 4);
    int c2 = c + 64;
    if (c2 < 112)
      *(float4*)(mrow + c2 * 4) = *(const float4*)(zrow + c2 * 4);
  }

  __syncthreads();
  const int sg = max(max(max(redi[0], redi[1]), max(redi[2], redi[3])),
                     max(max(redi[4], redi[5]), max(redi[6], redi[7])));

  // ---- Phase A: scores (split-K over kh) ----
  const int s_ = t >> 1;
  const int kh = t & 1;
  const bool valid = (s_ < sg);             // prefix-contiguous validity
  const float* krow = Zsnd + (size_t)idxs[s_] * C_ + CV + kh * 32;

  float sc[BSP];
  #pragma unroll
  for (int b = 0; b < BSP; b++) sc[b] = 0.0f;

  #pragma unroll
  for (int c = 0; c < 2; c++) {
    float4 k0 = *(const float4*)(krow + c * 16 + 0);
    float4 k1 = *(const float4*)(krow + c * 16 + 4);
    float4 k2 = *(const float4*)(krow + c * 16 + 8);
    float4 k3 = *(const float4*)(krow + c * 16 + 12);
    #pragma unroll
    for (int b = 0; b < BSP; b++) {
      const float* qb = qs + b * A_ + kh * 32 + c * 16;
      float4 q0 = *(const float4*)(qb + 0);
      float4 q1 = *(const float4*)(qb + 4);
      float4 q2 = *(const float4*)(qb + 8);
      float4 q3 = *(const float4*)(qb + 12);
      sc[b] += q0.x * k0.x + q0.y * k0.y + q0.z * k0.z + q0.w * k0.w
             + q1.x * k1.x + q1.y * k1.y + q1.z * k1.z + q1.w * k1.w
             + q2.x * k2.x + q2.y * k2.y + q2.z * k2.z + q2.w * k2.w
             + q3.x * k3.x + q3.y * k3.y + q3.z * k3.z + q3.w * k3.w;
    }
    __builtin_amdgcn_sched_barrier(0);      // cap live values (anti-spill)
  }
  #pragma unroll
  for (int b = 0; b < BSP; b++)
    sc[b] += __shfl_xor(sc[b], 1, 64);      // combine kh halves: full dot

  // ---- softmax over s (butterfly within wave, LDS across 8 waves) ----
  #pragma unroll
  for (int b = 0; b < BSP; b++) {
    float v = valid ? sc[b] : -INFINITY;
    #pragma unroll
    for (int off = 32; off > 0; off >>= 1)
      v = fmaxf(v, __shfl_xor(v, off, 64));
    if (lane == 0) red[wave * BSP + b] = v;
  }
  __syncthreads();

  float ex[BSP];
  #pragma unroll
  for (int b = 0; b < BSP; b++) {
    float gm = red[0 * BSP + b];
    #pragma unroll
    for (int w2 = 1; w2 < 8; w2++) gm = fmaxf(gm, red[w2 * BSP + b]);
    float e = valid ? __expf(sc[b] - gm) : 0.0f;
    ex[b] = e;
    float es = (kh == 0) ? e : 0.0f;        // count each s once
    #pragma unroll
    for (int off = 32; off > 0; off >>= 1)
      es += __shfl_xor(es, off, 64);
    if (lane == 0) red2[wave * BSP + b] = es;
  }
  __syncthreads();

  if (kh == 0) {
    float iv[BSP];
    #pragma unroll
    for (int b = 0; b < BSP; b++) {
      float gs = red2[0 * BSP + b];
      #pragma unroll
      for (int w2 = 1; w2 < 8; w2++) gs += red2[w2 * BSP + b];
      iv[b] = ex[b] / gs;
    }
    *(float4*)(attnT + s_ * BSP + 0) = make_float4(iv[0], iv[1], iv[2], iv[3]);
    *(float4*)(attnT + s_ * BSP + 4) = make_float4(iv[4], iv[5], iv[6], iv[7]);
  }
  __syncthreads();

  // ---- Phase B: weighted value sum (32 s per iter, 8 gathers in flight) ----
  const int ch = wave >> 1;                 // column chunk (0..3)
  const int sh = wave & 1;                  // s parity
  const int cl = lane & 31;                 // float4 column slot
  const int h  = lane >> 5;                 // s sub-parity
  const int c0 = ch * 128;
  const int sg32 = (sg + 31) & ~31;         // attnT==0 past sg -> pad is exact

  const float* vbase = Zsnd + c0 + cl * 4;  // + idx*C_ ; col <= 508 in-row
  float4 acc[BSP];
  #pragma unroll
  for (int b = 0; b < BSP; b++) acc[b] = make_float4(0.f, 0.f, 0.f, 0.f);

  for (int s0 = 0; s0 < sg32; s0 += 32) {
    float4 v[8];
    #pragma unroll
    for (int j = 0; j < 8; j++) {
      int so = s0 + 4 * j + 2 * sh + h;
      v[j] = *(const float4*)(vbase + (size_t)idxs[so] * C_);
    }
    #pragma unroll
    for (int j = 0; j < 8; j++) {
      int so = s0 + 4 * j + 2 * sh + h;
      float4 w0 = *(const float4*)(attnT + so * BSP + 0);   // b 0..3 (broadcast)
      float4 w1 = *(const float4*)(attnT + so * BSP + 4);   // b 4..7
      float4 vv = v[j];
      acc[0].x += w0.x * vv.x; acc[0].y += w0.x * vv.y; acc[0].z += w0.x * vv.z; acc[0].w += w0.x * vv.w;
      acc[1].x += w0.y * vv.x; acc[1].y += w0.y * vv.y; acc[1].z += w0.y * vv.z; acc[1].w += w0.y * vv.w;
      acc[2].x += w0.z * vv.x; acc[2].y += w0.z * vv.y; acc[2].z += w0.z * vv.z; acc[2].w += w0.z * vv.w;
      acc[3].x += w0.w * vv.x; acc[3].y += w0.w * vv.y; acc[3].z += w0.w * vv.z; acc[3].w += w0.w * vv.w;
      acc[4].x += w1.x * vv.x; acc[4].y += w1.x * vv.y; acc[4].z += w1.x * vv.z; acc[4].w += w1.x * vv.w;
      acc[5].x += w1.y * vv.x; acc[5].y += w1.y * vv.y; acc[5].z += w1.y * vv.z; acc[5].w += w1.y * vv.w;
      acc[6].x += w1.z * vv.x; acc[6].y += w1.z * vv.y; acc[6].z += w1.z * vv.z; acc[6].w += w1.z * vv.w;
      acc[7].x += w1.w * vv.x; acc[7].y += w1.w * vv.y; acc[7].z += w1.w * vv.z; acc[7].w += w1.w * vv.w;
    }
  }

  // ---- cross-wave combine: sh==1 partials -> LDS, sh==0 adds + h-shfl ----
  if (sh == 1) {
    #pragma unroll
    for (int b = 0; b < BSP; b++)
      *(float4*)(redS + (((size_t)ch * BSP + b) * 64 + lane) * 4) = acc[b];
  }
  __syncthreads();
  if (sh == 0) {
    #pragma unroll
    for (int b = 0; b < BSP; b++) {
      float4 o = *(const float4*)(redS + (((size_t)ch * BSP + b) * 64 + lane) * 4);
      acc[b].x += o.x; acc[b].y += o.y; acc[b].z += o.z; acc[b].w += o.w;
      acc[b].x += __shfl_xor(acc[b].x, 32, 64);
      acc[b].y += __shfl_xor(acc[b].y, 32, 64);
      acc[b].z += __shfl_xor(acc[b].z, 32, 64);
      acc[b].w += __shfl_xor(acc[b].w, 32, 64);
    }
    if (h == 0 && c0 + cl * 4 < CV) {
      float* obase = Msnd + (size_t)g * (B_ * CV) + (size_t)b0 * CV + c0 + cl * 4;
      #pragma unroll
      for (int b = 0; b < BSP; b++)
        *(float4*)(obase + b * CV) = acc[b];
    }
  }
}

extern "C" void kernel_launch(void* const* d_in, const int* in_sizes, int n_in,
                              void* d_out, int out_size, void* d_ws, size_t ws_size,
                              hipStream_t stream) {
  const float* Zimg   = (const float*)d_in[0];
  const float* Zsnd   = (const float*)d_in[1];
  const int*   padidx = (const int*)d_in[2];
  // d_in[3] = pad_mask (unused; validity derived from pad_idx)
  // d_in[4] = attn_dims (constant 64)

  const int N    = in_sizes[1] / C_;     // rows in Z_snd
  const int Smax = in_sizes[2] / G_;     // padded sequence length (== 256)

  float* z     = (float*)d_ws;                            // B*C fp32
  int*   sgArr = (int*)(z + B_ * C_);                     // 256 ints
  int*   grank = sgArr + G_;                              // 256 ints
  float* Mimg = (float*)d_out;
  float* Msnd = Mimg + (size_t)G_ * B_ * CV;

  meanpool_kernel<<<(B_ * C_) / 4, 256, 0, stream>>>(Zimg, z, padidx, sgArr, Smax, N);
  sched_kernel<<<1, 256, 0, stream>>>(sgArr, grank);
  fused_kernel<<<G_ * 2, 512, 0, stream>>>(Zsnd, padidx, z, grank, Mimg, Msnd, Smax, N);
}